// Round 9
// baseline (1250.010 us; speedup 1.0000x reference)
//
#include <hip/hip_runtime.h>
#include <hip/hip_bf16.h>

// Problem constants
#define BB 128
#define LL 256
#define CC 126
#define DD 128   // encoder width
#define HH 8
#define FFF 512
#define NLL 3
// rows = B*L = 32768

typedef __bf16 bf16x8 __attribute__((ext_vector_type(8)));
typedef float  f32x4  __attribute__((ext_vector_type(4)));

static __device__ __forceinline__ f32x4 mfma16(bf16x8 a, bf16x8 b, f32x4 c) {
    return __builtin_amdgcn_mfma_f32_16x16x32_bf16(a, b, c, 0, 0, 0);
}

// ---------------------------------------------------------------------------
// Weight packing: QKV -> Wt [NL][1536][128] bf16 (rows: q 0..511, k 512..1023, v 1024..1535),
// each row K-contiguous (transposed). bqk [NL][1024], bvp [NL][512] fp32.
__global__ void pack_qkv(const float* __restrict__ Wq, const float* __restrict__ Wk,
                         const float* __restrict__ Wv, const float* __restrict__ bq,
                         const float* __restrict__ bk, const float* __restrict__ bv,
                         __bf16* __restrict__ Wt, float* __restrict__ bqk, float* __restrict__ bvp)
{
    int idx = blockIdx.x * 256 + threadIdx.x;
    if (idx >= NLL * 1536 * 128) return;
    int i = idx / (1536 * 128);
    int r = idx % (1536 * 128);
    int c = r >> 7, d = r & 127;
    int which = c >> 9, hh = (c >> 6) & 7, kk = c & 63;
    const float* W = (which == 0) ? Wq : (which == 1) ? Wk : Wv;
    Wt[idx] = (__bf16)W[(((size_t)i * HH + hh) * DD + d) * 64 + kk];
    if (d == 0) {
        float bvv = ((which == 0) ? bq : (which == 1) ? bk : bv)[(i * HH + hh) * 64 + kk];
        if (which < 2) bqk[i * 1024 + c] = bvv;
        else           bvp[i * 512 + (c - 1024)] = bvv;
    }
}

// Wo [NL][512][128] -> Wot [NL][128][512]; W1 [NL][128][512] -> W1t [NL][512][128];
// W2 [NL][512][128] -> W2t [NL][128][512]   (all bf16, transposed = [N][K] K-contig)
__global__ void pack_ffn(const float* __restrict__ Wo, const float* __restrict__ W1,
                         const float* __restrict__ W2, __bf16* __restrict__ Wot,
                         __bf16* __restrict__ W1t, __bf16* __restrict__ W2t)
{
    int idx = blockIdx.x * 256 + threadIdx.x;
    if (idx >= 3 * NLL * 65536) return;
    int which = idx / (NLL * 65536);
    int r = idx % (NLL * 65536);
    int i = r / 65536, e = r % 65536;
    if (which == 0) {
        int dout = e >> 9, hv = e & 511;
        Wot[(size_t)i * 65536 + e] = (__bf16)Wo[(size_t)i * 65536 + hv * 128 + dout];
    } else if (which == 1) {
        int f = e >> 7, d = e & 127;
        W1t[(size_t)i * 65536 + e] = (__bf16)W1[(size_t)i * 65536 + d * 512 + f];
    } else {
        int d = e >> 9, f = e & 511;
        W2t[(size_t)i * 65536 + e] = (__bf16)W2[(size_t)i * 65536 + f * 128 + d];
    }
}

// dW1 [32768][512] f32 -> dW1t [512][32768] bf16 (LDS-tiled transpose)
__global__ __launch_bounds__(256) void trans_dw1(const float* __restrict__ src, __bf16* __restrict__ dst)
{
    __shared__ __bf16 tile[64][65];
    int bx = blockIdx.x;   // 8 tiles over 512
    int by = blockIdx.y;   // 512 tiles over 32768
    int tc = threadIdx.x & 63, tr = threadIdx.x >> 6;
    #pragma unroll
    for (int i = 0; i < 16; i++) {
        int r = i * 4 + tr;
        tile[tc][r] = (__bf16)src[(size_t)(by * 64 + r) * 512 + bx * 64 + tc];
    }
    __syncthreads();
    #pragma unroll
    for (int i = 0; i < 16; i++) {
        int r = i * 4 + tr;
        dst[(size_t)(bx * 64 + r) * 32768 + by * 64 + tc] = tile[r][tc];
    }
}

// ---------------------------------------------------------------------------
// Time2Vector: one wave per token row; writes fp32 and bf16 copies of h
__global__ __launch_bounds__(256) void t2v_k(const float* __restrict__ x,
                                             const float* __restrict__ wl, const float* __restrict__ bl,
                                             const float* __restrict__ wp, const float* __restrict__ bp,
                                             float* __restrict__ h, __bf16* __restrict__ hb)
{
    int w = threadIdx.x >> 6, lane = threadIdx.x & 63;
    int row = blockIdx.x * 4 + w;
    int l = row & (LL - 1);
    const float* xr = x + (size_t)row * CC;
    float sum = xr[lane];
    if (lane + 64 < CC) sum += xr[lane + 64];
    #pragma unroll
    for (int off = 32; off; off >>= 1) sum += __shfl_xor(sum, off);
    float t = sum * (1.0f / CC);
    float* hr = h + (size_t)row * DD;
    __bf16* hbr = hb + (size_t)row * DD;
    #pragma unroll
    for (int cc = 0; cc < 2; cc++) {
        int c = lane * 2 + cc;
        float v;
        if (c == 0)      v = wl[l] * t + bl[l];
        else if (c == 1) v = sinf(wp[l] * t + bp[l]);
        else             v = xr[c - 2];
        hr[c] = v;
        hbr[c] = (__bf16)v;
    }
}

// ---------------------------------------------------------------------------
// MFMA GEMM: C[M,N] = A[M,K] @ Bt[N,K]^T (+bias). BM=BN=128, BK=64, 4 waves.
// All M,N multiples of 128; K multiples of 64. BIASMODE: 0 none, 1 col, 2 row.
template <typename TC, int BIASMODE, bool RELU, bool ATOMIC>
__global__ __launch_bounds__(256) void mgemm(const __bf16* __restrict__ A, const __bf16* __restrict__ Bt,
                                             const float* __restrict__ bias, TC* __restrict__ C,
                                             int M, int N, int K, int ldc, int KC)
{
    __shared__ __bf16 As[128][72];
    __shared__ __bf16 Bs[128][72];
    const int t = threadIdx.x;
    const int lane = t & 63, w = t >> 6;
    const int wr = w >> 1, wc = w & 1;
    const int col = lane & 15, g = lane >> 4;
    const int m0 = blockIdx.y * 128, n0 = blockIdx.x * 128;
    const int kbeg = blockIdx.z * KC;
    const int kend = min(K, kbeg + KC);
    f32x4 acc[4][4] = {};

    for (int kt = kbeg; kt < kend; kt += 64) {
        #pragma unroll
        for (int i = 0; i < 4; i++) {
            int c = i * 256 + t;
            int r = c >> 3, cc = c & 7;
            *reinterpret_cast<uint4*>(&As[r][cc * 8]) =
                *reinterpret_cast<const uint4*>(A + (size_t)(m0 + r) * K + kt + cc * 8);
            *reinterpret_cast<uint4*>(&Bs[r][cc * 8]) =
                *reinterpret_cast<const uint4*>(Bt + (size_t)(n0 + r) * K + kt + cc * 8);
        }
        __syncthreads();
        #pragma unroll
        for (int ks = 0; ks < 2; ks++) {
            bf16x8 af[4], bfr[4];
            #pragma unroll
            for (int mt = 0; mt < 4; mt++)
                af[mt] = *reinterpret_cast<const bf16x8*>(&As[wr * 64 + mt * 16 + col][ks * 32 + g * 8]);
            #pragma unroll
            for (int nt = 0; nt < 4; nt++)
                bfr[nt] = *reinterpret_cast<const bf16x8*>(&Bs[wc * 64 + nt * 16 + col][ks * 32 + g * 8]);
            #pragma unroll
            for (int mt = 0; mt < 4; mt++)
                #pragma unroll
                for (int nt = 0; nt < 4; nt++)
                    acc[mt][nt] = mfma16(af[mt], bfr[nt], acc[mt][nt]);
        }
        __syncthreads();
    }

    #pragma unroll
    for (int mt = 0; mt < 4; mt++) {
        #pragma unroll
        for (int nt = 0; nt < 4; nt++) {
            #pragma unroll
            for (int r = 0; r < 4; r++) {
                int m = m0 + wr * 64 + mt * 16 + g * 4 + r;
                int n = n0 + wc * 64 + nt * 16 + col;
                float v = acc[mt][nt][r];
                if constexpr (ATOMIC) {
                    atomicAdd((float*)&C[(size_t)m * ldc + n], v);
                } else {
                    if constexpr (BIASMODE == 1) v += bias[n];
                    if constexpr (BIASMODE == 2) v += bias[m];
                    if constexpr (RELU) v = fmaxf(v, 0.f);
                    if constexpr (__is_same(TC, float)) C[(size_t)m * ldc + n] = v;
                    else                                C[(size_t)m * ldc + n] = (__bf16)v;
                }
            }
        }
    }
}

// ---------------------------------------------------------------------------
// Fused MFMA GEMM + residual + LayerNorm. N=128 fixed (one full LN row per tile).
// 512 threads / 8 waves (4x2 wave grid) for 2 waves/SIMD at 256 blocks.
// C = A[M,K] @ Bt[128,K]^T; v = C + bias[n] + resid[m][n]; out = g*(v-mean)/sqrt(var+eps)+be.
template <bool WF32>
__global__ __launch_bounds__(512) void mgemm_ln(const __bf16* __restrict__ A, const __bf16* __restrict__ Bt,
                                                const float* __restrict__ bias, const float* __restrict__ resid,
                                                const float* __restrict__ g_, const float* __restrict__ be,
                                                float* __restrict__ outf, __bf16* __restrict__ outb, int K)
{
    __shared__ __bf16 As[128][72];
    __shared__ __bf16 Bs[128][72];
    __shared__ float lnp[128][2][2];   // [row][wc][{sum,sumsq}]
    const int t = threadIdx.x;
    const int lane = t & 63, w = t >> 6;
    const int wr = w >> 1, wc = w & 1;           // 4 row-strips x 2 col-halves
    const int col = lane & 15, g = lane >> 4;
    const int m0 = blockIdx.x * 128;
    f32x4 acc[2][4] = {};

    for (int kt = 0; kt < K; kt += 64) {
        #pragma unroll
        for (int i = 0; i < 2; i++) {
            int c = i * 512 + t;
            int r = c >> 3, cc = c & 7;
            *reinterpret_cast<uint4*>(&As[r][cc * 8]) =
                *reinterpret_cast<const uint4*>(A + (size_t)(m0 + r) * K + kt + cc * 8);
            *reinterpret_cast<uint4*>(&Bs[r][cc * 8]) =
                *reinterpret_cast<const uint4*>(Bt + (size_t)r * K + kt + cc * 8);
        }
        __syncthreads();
        #pragma unroll
        for (int ks = 0; ks < 2; ks++) {
            bf16x8 af[2], bfr[4];
            #pragma unroll
            for (int mt = 0; mt < 2; mt++)
                af[mt] = *reinterpret_cast<const bf16x8*>(&As[wr * 32 + mt * 16 + col][ks * 32 + g * 8]);
            #pragma unroll
            for (int nt = 0; nt < 4; nt++)
                bfr[nt] = *reinterpret_cast<const bf16x8*>(&Bs[wc * 64 + nt * 16 + col][ks * 32 + g * 8]);
            #pragma unroll
            for (int mt = 0; mt < 2; mt++)
                #pragma unroll
                for (int nt = 0; nt < 4; nt++)
                    acc[mt][nt] = mfma16(af[mt], bfr[nt], acc[mt][nt]);
        }
        __syncthreads();
    }

    // v = C + bias + resid (into acc), then per-row partial reduction
    #pragma unroll
    for (int mt = 0; mt < 2; mt++) {
        #pragma unroll
        for (int r = 0; r < 4; r++) {
            int lm = wr * 32 + mt * 16 + g * 4 + r;
            int m = m0 + lm;
            float s = 0.f, q = 0.f;
            #pragma unroll
            for (int nt = 0; nt < 4; nt++) {
                int n = wc * 64 + nt * 16 + col;
                float v = acc[mt][nt][r] + bias[n] + resid[(size_t)m * DD + n];
                acc[mt][nt][r] = v;
                s += v;
                q += v * v;
            }
            #pragma unroll
            for (int off = 1; off < 16; off <<= 1) {
                s += __shfl_xor(s, off);
                q += __shfl_xor(q, off);
            }
            if (col == 0) {
                lnp[lm][wc][0] = s;
                lnp[lm][wc][1] = q;
            }
        }
    }
    __syncthreads();

    #pragma unroll
    for (int mt = 0; mt < 2; mt++) {
        #pragma unroll
        for (int r = 0; r < 4; r++) {
            int lm = wr * 32 + mt * 16 + g * 4 + r;
            int m = m0 + lm;
            float sum = lnp[lm][0][0] + lnp[lm][1][0];
            float sq  = lnp[lm][0][1] + lnp[lm][1][1];
            float mean = sum * (1.f / DD);
            float var  = sq * (1.f / DD) - mean * mean;
            float inv  = rsqrtf(var + 1e-6f);
            #pragma unroll
            for (int nt = 0; nt < 4; nt++) {
                int n = wc * 64 + nt * 16 + col;
                float rv = g_[n] * (acc[mt][nt][r] - mean) * inv + be[n];
                if constexpr (WF32) outf[(size_t)m * DD + n] = rv;
                outb[(size_t)m * DD + n] = (__bf16)rv;
            }
        }
    }
}

// ---------------------------------------------------------------------------
// MFMA fused attention v5: one block per (b,h). K staged in LDS (36.9 KB);
// V^T read directly from L2 (32 KB/block, L2-resident -> staging it wasted
// 33.8 KB of LDS/occupancy). LDS 46.1 KB -> 3 blocks/CU (12 waves/CU).
// qkv [32768][1024] bf16 (q cols 0..511, k cols 512..1023); Vt [512][32768] bf16.
__global__ __launch_bounds__(256, 3) void mattn(const __bf16* __restrict__ qkv,
                                                const __bf16* __restrict__ Vt,
                                                __bf16* __restrict__ obuf)
{
    __shared__ __bf16 Ks[256][72];    // K tile, token-major (36.9 KB)
    __shared__ __bf16 P[4][16][72];   // per-wave P chunk     (9.2 KB)
    const int t = threadIdx.x;
    const int lane = t & 63, w = t >> 6;
    const int col = lane & 15, g = lane >> 4;
    const int h = blockIdx.x & 7, b = blockIdx.x >> 3;
    const size_t tb = (size_t)b * 256;

    // stage K: 256 rows x 64 dk (128 B per row, 16 B per lane-chunk)
    #pragma unroll
    for (int i = 0; i < 8; i++) {
        int e = i * 256 + t;
        int r = e >> 3, c = e & 7;
        *reinterpret_cast<uint4*>(&Ks[r][c * 8]) =
            *reinterpret_cast<const uint4*>(qkv + (tb + r) * 1024 + 512 + h * 64 + c * 8);
    }
    __syncthreads();

    for (int qt = 0; qt < 4; qt++) {
        const int q0 = qt * 64 + w * 16;

        // Q fragments (A operand) straight from global/L2
        bf16x8 qf[2];
        #pragma unroll
        for (int ks = 0; ks < 2; ks++)
            qf[ks] = *reinterpret_cast<const bf16x8*>(
                qkv + (tb + q0 + col) * 1024 + h * 64 + ks * 32 + g * 8);

        // S = Q K^T (full 256-key row per wave), K from LDS
        f32x4 acc[16];
        #pragma unroll
        for (int nt = 0; nt < 16; nt++)
            acc[nt] = f32x4{0.f, 0.f, 0.f, 0.f};

        #pragma unroll
        for (int nt = 0; nt < 16; nt++) {
            bf16x8 kf0 = *reinterpret_cast<const bf16x8*>(&Ks[nt * 16 + col][g * 8]);
            bf16x8 kf1 = *reinterpret_cast<const bf16x8*>(&Ks[nt * 16 + col][32 + g * 8]);
            acc[nt] = mfma16(qf[0], kf0, acc[nt]);
            acc[nt] = mfma16(qf[1], kf1, acc[nt]);
        }

        // softmax over keys (row (g*4+r), cols across 16 lanes x 16 nt)
        float mx[4], den[4];
        #pragma unroll
        for (int r = 0; r < 4; r++) {
            float m = -1e30f;
            #pragma unroll
            for (int nt = 0; nt < 16; nt++) m = fmaxf(m, acc[nt][r]);
            #pragma unroll
            for (int off = 1; off < 16; off <<= 1) m = fmaxf(m, __shfl_xor(m, off));
            mx[r] = m;
        }
        #pragma unroll
        for (int r = 0; r < 4; r++) {
            float s = 0.f;
            #pragma unroll
            for (int nt = 0; nt < 16; nt++) {
                float p = __expf((acc[nt][r] - mx[r]) * 0.125f);
                acc[nt][r] = p;
                s += p;
            }
            #pragma unroll
            for (int off = 1; off < 16; off <<= 1) s += __shfl_xor(s, off);
            den[r] = s;
        }

        // O = P V in 4 chunks of 64 keys; P staged through per-wave LDS; V from L2
        f32x4 o[4];
        #pragma unroll
        for (int dt = 0; dt < 4; dt++)
            o[dt] = f32x4{0.f, 0.f, 0.f, 0.f};

        #pragma unroll
        for (int kc = 0; kc < 4; kc++) {
            #pragma unroll
            for (int nt2 = 0; nt2 < 4; nt2++)
                #pragma unroll
                for (int r = 0; r < 4; r++)
                    P[w][g * 4 + r][nt2 * 16 + col] = (__bf16)acc[kc * 4 + nt2][r];

            #pragma unroll
            for (int ks = 0; ks < 2; ks++) {
                bf16x8 pf = *reinterpret_cast<const bf16x8*>(&P[w][col][ks * 32 + g * 8]);
                #pragma unroll
                for (int dt = 0; dt < 4; dt++) {
                    bf16x8 vf = *reinterpret_cast<const bf16x8*>(
                        Vt + (size_t)(h * 64 + dt * 16 + col) * 32768 + tb + kc * 64 + ks * 32 + g * 8);
                    o[dt] = mfma16(pf, vf, o[dt]);
                }
            }
        }

        // normalize + store
        #pragma unroll
        for (int r = 0; r < 4; r++) {
            float inv = 1.f / den[r];
            #pragma unroll
            for (int dt = 0; dt < 4; dt++)
                obuf[(tb + q0 + g * 4 + r) * 512 + h * 64 + dt * 16 + col] =
                    (__bf16)(o[dt][r] * inv);
        }
    }
}

__global__ void zero_k(float* p, int n)
{
    int i = blockIdx.x * 256 + threadIdx.x;
    if (i < n) p[i] = 0.f;
}

// ---------------------------------------------------------------------------
// Head final layer: out[128][126] = relu(t1 + db1) @ dW2 + db2.
__global__ __launch_bounds__(256) void head2_k(const float* __restrict__ t1, const float* __restrict__ db1,
                                               const float* __restrict__ dW2, const float* __restrict__ db2,
                                               float* __restrict__ out)
{
    __shared__ float As[512];
    const int m = blockIdx.x, t = threadIdx.x;
    #pragma unroll
    for (int i = 0; i < 2; i++) {
        int k = i * 256 + t;
        As[k] = fmaxf(t1[m * 512 + k] + db1[k], 0.f);
    }
    __syncthreads();
    if (t < 126) {
        float s = 0.f;
        #pragma unroll 8
        for (int k = 0; k < 512; k++)
            s = fmaf(As[k], dW2[k * 126 + t], s);
        out[m * 126 + t] = s + db2[t];
    }
}

// ---------------------------------------------------------------------------
extern "C" void kernel_launch(void* const* d_in, const int* in_sizes, int n_in,
                              void* d_out, int out_size, void* d_ws, size_t ws_size,
                              hipStream_t stream)
{
    const float* x   = (const float*)d_in[0];
    const float* wl  = (const float*)d_in[1];
    const float* bl  = (const float*)d_in[2];
    const float* wp  = (const float*)d_in[3];
    const float* bp  = (const float*)d_in[4];
    const float* Wq  = (const float*)d_in[5];
    const float* bq  = (const float*)d_in[6];
    const float* Wk  = (const float*)d_in[7];
    const float* bk  = (const float*)d_in[8];
    const float* Wv  = (const float*)d_in[9];
    const float* bv  = (const float*)d_in[10];
    const float* Wo  = (const float*)d_in[11];
    const float* bo  = (const float*)d_in[12];
    const float* g1  = (const float*)d_in[13];
    const float* be1 = (const float*)d_in[14];
    const float* W1  = (const float*)d_in[15];
    const float* b1  = (const float*)d_in[16];
    const float* W2  = (const float*)d_in[17];
    const float* b2  = (const float*)d_in[18];
    const float* g2  = (const float*)d_in[19];
    const float* be2 = (const float*)d_in[20];
    const float* dW1 = (const float*)d_in[21];
    const float* db1 = (const float*)d_in[22];
    const float* dW2 = (const float*)d_in[23];
    const float* db2 = (const float*)d_in[24];
    float* out = (float*)d_out;

    // workspace layout (total 187,189,248 B == round-1-proven footprint)
    char* ws = (char*)d_ws;
    float*  h_f32   = (float*)(ws);                          // 16.78 MB
    __bf16* h_b     = (__bf16*)(ws + 33554432);              //  8.39 MB
    __bf16* h1_b    = (__bf16*)(ws + 41943040);              //  8.39 MB
    __bf16* qkv     = (__bf16*)(ws + 50331648);              // 67.11 MB  [32768][1024]
    __bf16* buf512  = (__bf16*)(ws + 117440512);             // 33.55 MB  Vt [512][32768] / ffmid [32768][512]
    __bf16* obuf    = (__bf16*)(ws + 150994944);             // 33.55 MB  [32768][512]; later dW1t [512][32768]
    __bf16* Wtqkv   = (__bf16*)(ws + 184549376);             //  1.18 MB  [3][1536][128]
    __bf16* Wot     = (__bf16*)(ws + 185729024);             //  0.39 MB
    __bf16* W1t     = (__bf16*)(ws + 186122240);             //  0.39 MB
    __bf16* W2t     = (__bf16*)(ws + 186515456);             //  0.39 MB
    float*  bqk     = (float*)(ws + 186908672);              // 12 KB
    float*  bvp     = (float*)(ws + 186920960);              //  6 KB
    float*  t1      = (float*)(ws + 186927104);              //  0.26 MB [128][512]
    __bf16* dW1t    = obuf;                                  // alias (obuf dead after last O-proj)

    pack_qkv<<<(NLL * 1536 * 128 + 255) / 256, 256, 0, stream>>>(Wq, Wk, Wv, bq, bk, bv, Wtqkv, bqk, bvp);
    pack_ffn<<<(3 * NLL * 65536 + 255) / 256, 256, 0, stream>>>(Wo, W1, W2, Wot, W1t, W2t);
    t2v_k<<<8192, 256, 0, stream>>>(x, wl, bl, wp, bp, h_f32, h_b);

    for (int i = 0; i < NLL; i++) {
        // QK projection: [32768,128] @ [128,1024] -> qkv
        mgemm<__bf16, 1, false, false><<<dim3(8, 256, 1), 256, 0, stream>>>(
            h_b, Wtqkv + (size_t)i * 1536 * 128, bqk + i * 1024, qkv, 32768, 1024, 128, 1024, 128);
        // V^T projection: [512,128] @ [128,32768] -> Vt (row bias)
        mgemm<__bf16, 2, false, false><<<dim3(256, 4, 1), 256, 0, stream>>>(
            Wtqkv + (size_t)i * 1536 * 128 + 1024 * 128, h_b, bvp + i * 512, buf512, 512, 32768, 128, 32768, 128);
        // fused MFMA attention (one block per (b,h))
        mattn<<<dim3(BB * HH), 256, 0, stream>>>(qkv, buf512, obuf);
        // fused O-proj + residual + LN1 -> h1_b
        mgemm_ln<false><<<dim3(256), 512, 0, stream>>>(
            obuf, Wot + (size_t)i * 65536, bo + i * DD, h_f32,
            g1 + i * DD, be1 + i * DD, nullptr, h1_b, 512);
        // FFN1 + relu: [32768,128] @ [128,512] -> ffmid (bf16)
        mgemm<__bf16, 1, true, false><<<dim3(4, 256, 1), 256, 0, stream>>>(
            h1_b, W1t + (size_t)i * 65536, b1 + i * FFF, buf512, 32768, 512, 128, 512, 128);
        // fused FFN2 + residual + LN2 -> h_f32 (in-place) + h_b
        mgemm_ln<true><<<dim3(256), 512, 0, stream>>>(
            buf512, W2t + (size_t)i * 65536, b2 + i * DD, h_f32,
            g2 + i * DD, be2 + i * DD, h_f32, h_b, 512);
    }

    // head
    trans_dw1<<<dim3(8, 512, 1), 256, 0, stream>>>(dW1, dW1t);
    zero_k<<<256, 256, 0, stream>>>(t1, 128 * 512);
    mgemm<float, 0, false, true><<<dim3(4, 1, 64), 256, 0, stream>>>(
        h_b, dW1t, nullptr, t1, 128, 512, 32768, 512, 512);
    head2_k<<<dim3(128), 256, 0, stream>>>(t1, db1, dW2, db2, out);
}

// Round 10
// 674.319 us; speedup vs baseline: 1.8537x; 1.8537x over previous
//
#include <hip/hip_runtime.h>
#include <hip/hip_bf16.h>

// Problem constants
#define BB 128
#define LL 256
#define CC 126
#define DD 128   // encoder width
#define HH 8
#define FFF 512
#define NLL 3
// rows = B*L = 32768

typedef __bf16 bf16x8 __attribute__((ext_vector_type(8)));
typedef float  f32x4  __attribute__((ext_vector_type(4)));

static __device__ __forceinline__ f32x4 mfma16(bf16x8 a, bf16x8 b, f32x4 c) {
    return __builtin_amdgcn_mfma_f32_16x16x32_bf16(a, b, c, 0, 0, 0);
}

// ---------------------------------------------------------------------------
// Weight packing: QKV -> Wt [NL][1536][128] bf16 (rows: q 0..511, k 512..1023, v 1024..1535),
// each row K-contiguous (transposed). bqk [NL][1024], bvp [NL][512] fp32.
__global__ void pack_qkv(const float* __restrict__ Wq, const float* __restrict__ Wk,
                         const float* __restrict__ Wv, const float* __restrict__ bq,
                         const float* __restrict__ bk, const float* __restrict__ bv,
                         __bf16* __restrict__ Wt, float* __restrict__ bqk, float* __restrict__ bvp)
{
    int idx = blockIdx.x * 256 + threadIdx.x;
    if (idx >= NLL * 1536 * 128) return;
    int i = idx / (1536 * 128);
    int r = idx % (1536 * 128);
    int c = r >> 7, d = r & 127;
    int which = c >> 9, hh = (c >> 6) & 7, kk = c & 63;
    const float* W = (which == 0) ? Wq : (which == 1) ? Wk : Wv;
    Wt[idx] = (__bf16)W[(((size_t)i * HH + hh) * DD + d) * 64 + kk];
    if (d == 0) {
        float bvv = ((which == 0) ? bq : (which == 1) ? bk : bv)[(i * HH + hh) * 64 + kk];
        if (which < 2) bqk[i * 1024 + c] = bvv;
        else           bvp[i * 512 + (c - 1024)] = bvv;
    }
}

// Wo [NL][512][128] -> Wot [NL][128][512]; W1 [NL][128][512] -> W1t [NL][512][128];
// W2 [NL][512][128] -> W2t [NL][128][512]   (all bf16, transposed = [N][K] K-contig)
__global__ void pack_ffn(const float* __restrict__ Wo, const float* __restrict__ W1,
                         const float* __restrict__ W2, __bf16* __restrict__ Wot,
                         __bf16* __restrict__ W1t, __bf16* __restrict__ W2t)
{
    int idx = blockIdx.x * 256 + threadIdx.x;
    if (idx >= 3 * NLL * 65536) return;
    int which = idx / (NLL * 65536);
    int r = idx % (NLL * 65536);
    int i = r / 65536, e = r % 65536;
    if (which == 0) {
        int dout = e >> 9, hv = e & 511;
        Wot[(size_t)i * 65536 + e] = (__bf16)Wo[(size_t)i * 65536 + hv * 128 + dout];
    } else if (which == 1) {
        int f = e >> 7, d = e & 127;
        W1t[(size_t)i * 65536 + e] = (__bf16)W1[(size_t)i * 65536 + d * 512 + f];
    } else {
        int d = e >> 9, f = e & 511;
        W2t[(size_t)i * 65536 + e] = (__bf16)W2[(size_t)i * 65536 + f * 128 + d];
    }
}

// dW1 [32768][512] f32 -> dW1t [512][32768] bf16 (LDS-tiled transpose)
__global__ __launch_bounds__(256) void trans_dw1(const float* __restrict__ src, __bf16* __restrict__ dst)
{
    __shared__ __bf16 tile[64][65];
    int bx = blockIdx.x;   // 8 tiles over 512
    int by = blockIdx.y;   // 512 tiles over 32768
    int tc = threadIdx.x & 63, tr = threadIdx.x >> 6;
    #pragma unroll
    for (int i = 0; i < 16; i++) {
        int r = i * 4 + tr;
        tile[tc][r] = (__bf16)src[(size_t)(by * 64 + r) * 512 + bx * 64 + tc];
    }
    __syncthreads();
    #pragma unroll
    for (int i = 0; i < 16; i++) {
        int r = i * 4 + tr;
        dst[(size_t)(bx * 64 + r) * 32768 + by * 64 + tc] = tile[r][tc];
    }
}

// ---------------------------------------------------------------------------
// Time2Vector: one wave per token row; writes fp32 and bf16 copies of h
__global__ __launch_bounds__(256) void t2v_k(const float* __restrict__ x,
                                             const float* __restrict__ wl, const float* __restrict__ bl,
                                             const float* __restrict__ wp, const float* __restrict__ bp,
                                             float* __restrict__ h, __bf16* __restrict__ hb)
{
    int w = threadIdx.x >> 6, lane = threadIdx.x & 63;
    int row = blockIdx.x * 4 + w;
    int l = row & (LL - 1);
    const float* xr = x + (size_t)row * CC;
    float sum = xr[lane];
    if (lane + 64 < CC) sum += xr[lane + 64];
    #pragma unroll
    for (int off = 32; off; off >>= 1) sum += __shfl_xor(sum, off);
    float t = sum * (1.0f / CC);
    float* hr = h + (size_t)row * DD;
    __bf16* hbr = hb + (size_t)row * DD;
    #pragma unroll
    for (int cc = 0; cc < 2; cc++) {
        int c = lane * 2 + cc;
        float v;
        if (c == 0)      v = wl[l] * t + bl[l];
        else if (c == 1) v = sinf(wp[l] * t + bp[l]);
        else             v = xr[c - 2];
        hr[c] = v;
        hbr[c] = (__bf16)v;
    }
}

// ---------------------------------------------------------------------------
// MFMA GEMM: C[M,N] = A[M,K] @ Bt[N,K]^T (+bias). BM=BN=128, BK=64, 4 waves.
// All M,N multiples of 128; K multiples of 64. BIASMODE: 0 none, 1 col, 2 row.
template <typename TC, int BIASMODE, bool RELU, bool ATOMIC>
__global__ __launch_bounds__(256) void mgemm(const __bf16* __restrict__ A, const __bf16* __restrict__ Bt,
                                             const float* __restrict__ bias, TC* __restrict__ C,
                                             int M, int N, int K, int ldc, int KC)
{
    __shared__ __bf16 As[128][72];
    __shared__ __bf16 Bs[128][72];
    const int t = threadIdx.x;
    const int lane = t & 63, w = t >> 6;
    const int wr = w >> 1, wc = w & 1;
    const int col = lane & 15, g = lane >> 4;
    const int m0 = blockIdx.y * 128, n0 = blockIdx.x * 128;
    const int kbeg = blockIdx.z * KC;
    const int kend = min(K, kbeg + KC);
    f32x4 acc[4][4] = {};

    for (int kt = kbeg; kt < kend; kt += 64) {
        #pragma unroll
        for (int i = 0; i < 4; i++) {
            int c = i * 256 + t;
            int r = c >> 3, cc = c & 7;
            *reinterpret_cast<uint4*>(&As[r][cc * 8]) =
                *reinterpret_cast<const uint4*>(A + (size_t)(m0 + r) * K + kt + cc * 8);
            *reinterpret_cast<uint4*>(&Bs[r][cc * 8]) =
                *reinterpret_cast<const uint4*>(Bt + (size_t)(n0 + r) * K + kt + cc * 8);
        }
        __syncthreads();
        #pragma unroll
        for (int ks = 0; ks < 2; ks++) {
            bf16x8 af[4], bfr[4];
            #pragma unroll
            for (int mt = 0; mt < 4; mt++)
                af[mt] = *reinterpret_cast<const bf16x8*>(&As[wr * 64 + mt * 16 + col][ks * 32 + g * 8]);
            #pragma unroll
            for (int nt = 0; nt < 4; nt++)
                bfr[nt] = *reinterpret_cast<const bf16x8*>(&Bs[wc * 64 + nt * 16 + col][ks * 32 + g * 8]);
            #pragma unroll
            for (int mt = 0; mt < 4; mt++)
                #pragma unroll
                for (int nt = 0; nt < 4; nt++)
                    acc[mt][nt] = mfma16(af[mt], bfr[nt], acc[mt][nt]);
        }
        __syncthreads();
    }

    #pragma unroll
    for (int mt = 0; mt < 4; mt++) {
        #pragma unroll
        for (int nt = 0; nt < 4; nt++) {
            #pragma unroll
            for (int r = 0; r < 4; r++) {
                int m = m0 + wr * 64 + mt * 16 + g * 4 + r;
                int n = n0 + wc * 64 + nt * 16 + col;
                float v = acc[mt][nt][r];
                if constexpr (ATOMIC) {
                    atomicAdd((float*)&C[(size_t)m * ldc + n], v);
                } else {
                    if constexpr (BIASMODE == 1) v += bias[n];
                    if constexpr (BIASMODE == 2) v += bias[m];
                    if constexpr (RELU) v = fmaxf(v, 0.f);
                    if constexpr (__is_same(TC, float)) C[(size_t)m * ldc + n] = v;
                    else                                C[(size_t)m * ldc + n] = (__bf16)v;
                }
            }
        }
    }
}

// ---------------------------------------------------------------------------
// Fused MFMA GEMM + residual + LayerNorm. N=128 fixed (one full LN row per tile).
// 512 threads / 8 waves (4x2 wave grid) for 2 waves/SIMD at 256 blocks.
template <bool WF32>
__global__ __launch_bounds__(512) void mgemm_ln(const __bf16* __restrict__ A, const __bf16* __restrict__ Bt,
                                                const float* __restrict__ bias, const float* __restrict__ resid,
                                                const float* __restrict__ g_, const float* __restrict__ be,
                                                float* __restrict__ outf, __bf16* __restrict__ outb, int K)
{
    __shared__ __bf16 As[128][72];
    __shared__ __bf16 Bs[128][72];
    __shared__ float lnp[128][2][2];   // [row][wc][{sum,sumsq}]
    const int t = threadIdx.x;
    const int lane = t & 63, w = t >> 6;
    const int wr = w >> 1, wc = w & 1;           // 4 row-strips x 2 col-halves
    const int col = lane & 15, g = lane >> 4;
    const int m0 = blockIdx.x * 128;
    f32x4 acc[2][4] = {};

    for (int kt = 0; kt < K; kt += 64) {
        #pragma unroll
        for (int i = 0; i < 2; i++) {
            int c = i * 512 + t;
            int r = c >> 3, cc = c & 7;
            *reinterpret_cast<uint4*>(&As[r][cc * 8]) =
                *reinterpret_cast<const uint4*>(A + (size_t)(m0 + r) * K + kt + cc * 8);
            *reinterpret_cast<uint4*>(&Bs[r][cc * 8]) =
                *reinterpret_cast<const uint4*>(Bt + (size_t)r * K + kt + cc * 8);
        }
        __syncthreads();
        #pragma unroll
        for (int ks = 0; ks < 2; ks++) {
            bf16x8 af[2], bfr[4];
            #pragma unroll
            for (int mt = 0; mt < 2; mt++)
                af[mt] = *reinterpret_cast<const bf16x8*>(&As[wr * 32 + mt * 16 + col][ks * 32 + g * 8]);
            #pragma unroll
            for (int nt = 0; nt < 4; nt++)
                bfr[nt] = *reinterpret_cast<const bf16x8*>(&Bs[wc * 64 + nt * 16 + col][ks * 32 + g * 8]);
            #pragma unroll
            for (int mt = 0; mt < 2; mt++)
                #pragma unroll
                for (int nt = 0; nt < 4; nt++)
                    acc[mt][nt] = mfma16(af[mt], bfr[nt], acc[mt][nt]);
        }
        __syncthreads();
    }

    // v = C + bias + resid (into acc), then per-row partial reduction
    #pragma unroll
    for (int mt = 0; mt < 2; mt++) {
        #pragma unroll
        for (int r = 0; r < 4; r++) {
            int lm = wr * 32 + mt * 16 + g * 4 + r;
            int m = m0 + lm;
            float s = 0.f, q = 0.f;
            #pragma unroll
            for (int nt = 0; nt < 4; nt++) {
                int n = wc * 64 + nt * 16 + col;
                float v = acc[mt][nt][r] + bias[n] + resid[(size_t)m * DD + n];
                acc[mt][nt][r] = v;
                s += v;
                q += v * v;
            }
            #pragma unroll
            for (int off = 1; off < 16; off <<= 1) {
                s += __shfl_xor(s, off);
                q += __shfl_xor(q, off);
            }
            if (col == 0) {
                lnp[lm][wc][0] = s;
                lnp[lm][wc][1] = q;
            }
        }
    }
    __syncthreads();

    #pragma unroll
    for (int mt = 0; mt < 2; mt++) {
        #pragma unroll
        for (int r = 0; r < 4; r++) {
            int lm = wr * 32 + mt * 16 + g * 4 + r;
            int m = m0 + lm;
            float sum = lnp[lm][0][0] + lnp[lm][1][0];
            float sq  = lnp[lm][0][1] + lnp[lm][1][1];
            float mean = sum * (1.f / DD);
            float var  = sq * (1.f / DD) - mean * mean;
            float inv  = rsqrtf(var + 1e-6f);
            #pragma unroll
            for (int nt = 0; nt < 4; nt++) {
                int n = wc * 64 + nt * 16 + col;
                float rv = g_[n] * (acc[mt][nt][r] - mean) * inv + be[n];
                if constexpr (WF32) outf[(size_t)m * DD + n] = rv;
                outb[(size_t)m * DD + n] = (__bf16)rv;
            }
        }
    }
}

// ---------------------------------------------------------------------------
// MFMA fused attention v6: one block per (b,h), 8 waves x 16 q-rows x 2 passes.
// K and V^T staged in LDS once (the round-9 no-Vs experiment thrashed L2:
// 768 concurrent blocks x ~100KB >> 32MB L2 -> 421MB HBM fetch. Staging is
// load-bearing). Same 79KB LDS as the 4-wave version but 8 waves/block
// -> 16 waves/CU = 4 waves/SIMD. PV in 32-key chunks (halves P buffer).
__global__ __launch_bounds__(512, 4) void mattn(const __bf16* __restrict__ qkv,
                                                const __bf16* __restrict__ Vt,
                                                __bf16* __restrict__ obuf)
{
    __shared__ __bf16 Ks[256][72];    // K tile, token-major (36,864 B)
    __shared__ __bf16 Vs[64][264];    // V^T tile, d-major   (33,792 B)
    __shared__ __bf16 P[8][16][40];   // per-wave 32-key P chunk (10,240 B) -> 80,896 total
    const int t = threadIdx.x;
    const int lane = t & 63, w = t >> 6;      // w 0..7
    const int col = lane & 15, g = lane >> 4;
    const int h = blockIdx.x & 7, b = blockIdx.x >> 3;
    const size_t tb = (size_t)b * 256;

    // stage K: 256 rows x 64 dk (2048 uint4, 4 per thread)
    #pragma unroll
    for (int i = 0; i < 4; i++) {
        int e = i * 512 + t;
        int r = e >> 3, c = e & 7;
        *reinterpret_cast<uint4*>(&Ks[r][c * 8]) =
            *reinterpret_cast<const uint4*>(qkv + (tb + r) * 1024 + 512 + h * 64 + c * 8);
    }
    // stage V^T: 64 d-rows x 256 keys
    #pragma unroll
    for (int i = 0; i < 4; i++) {
        int e = i * 512 + t;
        int d = e >> 5, c = e & 31;
        *reinterpret_cast<uint4*>(&Vs[d][c * 8]) =
            *reinterpret_cast<const uint4*>(Vt + (size_t)(h * 64 + d) * 32768 + tb + c * 8);
    }
    __syncthreads();

    #pragma unroll
    for (int qt = 0; qt < 2; qt++) {
        const int q0 = qt * 128 + w * 16;

        // Q fragments (A operand) straight from global/L2
        bf16x8 qf[2];
        #pragma unroll
        for (int ks = 0; ks < 2; ks++)
            qf[ks] = *reinterpret_cast<const bf16x8*>(
                qkv + (tb + q0 + col) * 1024 + h * 64 + ks * 32 + g * 8);

        // S = Q K^T (full 256-key row per wave), K from LDS
        f32x4 acc[16];
        #pragma unroll
        for (int nt = 0; nt < 16; nt++)
            acc[nt] = f32x4{0.f, 0.f, 0.f, 0.f};

        __builtin_amdgcn_s_setprio(1);
        #pragma unroll
        for (int nt = 0; nt < 16; nt++) {
            bf16x8 kf0 = *reinterpret_cast<const bf16x8*>(&Ks[nt * 16 + col][g * 8]);
            bf16x8 kf1 = *reinterpret_cast<const bf16x8*>(&Ks[nt * 16 + col][32 + g * 8]);
            acc[nt] = mfma16(qf[0], kf0, acc[nt]);
            acc[nt] = mfma16(qf[1], kf1, acc[nt]);
        }
        __builtin_amdgcn_s_setprio(0);

        // softmax over keys (row (g*4+r), cols across 16 lanes x 16 nt)
        // exp2-folded: exp((s-m)*0.125) == exp2((s-m)*0.125*log2(e))
        float mx[4], den[4];
        #pragma unroll
        for (int r = 0; r < 4; r++) {
            float m = -1e30f;
            #pragma unroll
            for (int nt = 0; nt < 16; nt++) m = fmaxf(m, acc[nt][r]);
            #pragma unroll
            for (int off = 1; off < 16; off <<= 1) m = fmaxf(m, __shfl_xor(m, off));
            mx[r] = m;
        }
        #pragma unroll
        for (int r = 0; r < 4; r++) {
            float s = 0.f;
            #pragma unroll
            for (int nt = 0; nt < 16; nt++) {
                float p = exp2f((acc[nt][r] - mx[r]) * 0.18033688011112042f);
                acc[nt][r] = p;
                s += p;
            }
            #pragma unroll
            for (int off = 1; off < 16; off <<= 1) s += __shfl_xor(s, off);
            den[r] = s;
        }

        // O = P V in 8 chunks of 32 keys; P staged through per-wave LDS; V from LDS
        f32x4 o[4];
        #pragma unroll
        for (int dt = 0; dt < 4; dt++)
            o[dt] = f32x4{0.f, 0.f, 0.f, 0.f};

        #pragma unroll
        for (int kc = 0; kc < 8; kc++) {
            #pragma unroll
            for (int half = 0; half < 2; half++)
                #pragma unroll
                for (int r = 0; r < 4; r++)
                    P[w][g * 4 + r][half * 16 + col] = (__bf16)acc[kc * 2 + half][r];

            bf16x8 pf = *reinterpret_cast<const bf16x8*>(&P[w][col][g * 8]);
            __builtin_amdgcn_s_setprio(1);
            #pragma unroll
            for (int dt = 0; dt < 4; dt++) {
                bf16x8 vf = *reinterpret_cast<const bf16x8*>(
                    &Vs[dt * 16 + col][kc * 32 + g * 8]);
                o[dt] = mfma16(pf, vf, o[dt]);
            }
            __builtin_amdgcn_s_setprio(0);
        }

        // normalize + store
        #pragma unroll
        for (int r = 0; r < 4; r++) {
            float inv = 1.f / den[r];
            #pragma unroll
            for (int dt = 0; dt < 4; dt++)
                obuf[(tb + q0 + g * 4 + r) * 512 + h * 64 + dt * 16 + col] =
                    (__bf16)(o[dt][r] * inv);
        }
    }
}

__global__ void zero_k(float* p, int n)
{
    int i = blockIdx.x * 256 + threadIdx.x;
    if (i < n) p[i] = 0.f;
}

// ---------------------------------------------------------------------------
// Head final layer: out[128][126] = relu(t1 + db1) @ dW2 + db2.
__global__ __launch_bounds__(256) void head2_k(const float* __restrict__ t1, const float* __restrict__ db1,
                                               const float* __restrict__ dW2, const float* __restrict__ db2,
                                               float* __restrict__ out)
{
    __shared__ float As[512];
    const int m = blockIdx.x, t = threadIdx.x;
    #pragma unroll
    for (int i = 0; i < 2; i++) {
        int k = i * 256 + t;
        As[k] = fmaxf(t1[m * 512 + k] + db1[k], 0.f);
    }
    __syncthreads();
    if (t < 126) {
        float s = 0.f;
        #pragma unroll 8
        for (int k = 0; k < 512; k++)
            s = fmaf(As[k], dW2[k * 126 + t], s);
        out[m * 126 + t] = s + db2[t];
    }
}

// ---------------------------------------------------------------------------
extern "C" void kernel_launch(void* const* d_in, const int* in_sizes, int n_in,
                              void* d_out, int out_size, void* d_ws, size_t ws_size,
                              hipStream_t stream)
{
    const float* x   = (const float*)d_in[0];
    const float* wl  = (const float*)d_in[1];
    const float* bl  = (const float*)d_in[2];
    const float* wp  = (const float*)d_in[3];
    const float* bp  = (const float*)d_in[4];
    const float* Wq  = (const float*)d_in[5];
    const float* bq  = (const float*)d_in[6];
    const float* Wk  = (const float*)d_in[7];
    const float* bk  = (const float*)d_in[8];
    const float* Wv  = (const float*)d_in[9];
    const float* bv  = (const float*)d_in[10];
    const float* Wo  = (const float*)d_in[11];
    const float* bo  = (const float*)d_in[12];
    const float* g1  = (const float*)d_in[13];
    const float* be1 = (const float*)d_in[14];
    const float* W1  = (const float*)d_in[15];
    const float* b1  = (const float*)d_in[16];
    const float* W2  = (const float*)d_in[17];
    const float* b2  = (const float*)d_in[18];
    const float* g2  = (const float*)d_in[19];
    const float* be2 = (const float*)d_in[20];
    const float* dW1 = (const float*)d_in[21];
    const float* db1 = (const float*)d_in[22];
    const float* dW2 = (const float*)d_in[23];
    const float* db2 = (const float*)d_in[24];
    float* out = (float*)d_out;

    // workspace layout (total 187,189,248 B == round-1-proven footprint)
    char* ws = (char*)d_ws;
    float*  h_f32   = (float*)(ws);                          // 16.78 MB
    __bf16* h_b     = (__bf16*)(ws + 33554432);              //  8.39 MB
    __bf16* h1_b    = (__bf16*)(ws + 41943040);              //  8.39 MB
    __bf16* qkv     = (__bf16*)(ws + 50331648);              // 67.11 MB  [32768][1024]
    __bf16* buf512  = (__bf16*)(ws + 117440512);             // 33.55 MB  Vt [512][32768] / ffmid [32768][512]
    __bf16* obuf    = (__bf16*)(ws + 150994944);             // 33.55 MB  [32768][512]; later dW1t [512][32768]
    __bf16* Wtqkv   = (__bf16*)(ws + 184549376);             //  1.18 MB  [3][1536][128]
    __bf16* Wot     = (__bf16*)(ws + 185729024);             //  0.39 MB
    __bf16* W1t     = (__bf16*)(ws + 186122240);             //  0.39 MB
    __bf16* W2t     = (__bf16*)(ws + 186515456);             //  0.39 MB
    float*  bqk     = (float*)(ws + 186908672);              // 12 KB
    float*  bvp     = (float*)(ws + 186920960);              //  6 KB
    float*  t1      = (float*)(ws + 186927104);              //  0.26 MB [128][512]
    __bf16* dW1t    = obuf;                                  // alias (obuf dead after last O-proj)

    pack_qkv<<<(NLL * 1536 * 128 + 255) / 256, 256, 0, stream>>>(Wq, Wk, Wv, bq, bk, bv, Wtqkv, bqk, bvp);
    pack_ffn<<<(3 * NLL * 65536 + 255) / 256, 256, 0, stream>>>(Wo, W1, W2, Wot, W1t, W2t);
    t2v_k<<<8192, 256, 0, stream>>>(x, wl, bl, wp, bp, h_f32, h_b);

    for (int i = 0; i < NLL; i++) {
        // QK projection: [32768,128] @ [128,1024] -> qkv
        mgemm<__bf16, 1, false, false><<<dim3(8, 256, 1), 256, 0, stream>>>(
            h_b, Wtqkv + (size_t)i * 1536 * 128, bqk + i * 1024, qkv, 32768, 1024, 128, 1024, 128);
        // V^T projection: [512,128] @ [128,32768] -> Vt (row bias)
        mgemm<__bf16, 2, false, false><<<dim3(256, 4, 1), 256, 0, stream>>>(
            Wtqkv + (size_t)i * 1536 * 128 + 1024 * 128, h_b, bvp + i * 512, buf512, 512, 32768, 128, 32768, 128);
        // fused MFMA attention (one block per (b,h), 8 waves)
        mattn<<<dim3(BB * HH), 512, 0, stream>>>(qkv, buf512, obuf);
        // fused O-proj + residual + LN1 -> h1_b
        mgemm_ln<false><<<dim3(256), 512, 0, stream>>>(
            obuf, Wot + (size_t)i * 65536, bo + i * DD, h_f32,
            g1 + i * DD, be1 + i * DD, nullptr, h1_b, 512);
        // FFN1 + relu: [32768,128] @ [128,512] -> ffmid (bf16)
        mgemm<__bf16, 1, true, false><<<dim3(4, 256, 1), 256, 0, stream>>>(
            h1_b, W1t + (size_t)i * 65536, b1 + i * FFF, buf512, 32768, 512, 128, 512, 128);
        // fused FFN2 + residual + LN2 -> h_f32 (in-place) + h_b
        mgemm_ln<true><<<dim3(256), 512, 0, stream>>>(
            buf512, W2t + (size_t)i * 65536, b2 + i * DD, h_f32,
            g2 + i * DD, be2 + i * DD, h_f32, h_b, 512);
    }

    // head
    trans_dw1<<<dim3(8, 512, 1), 256, 0, stream>>>(dW1, dW1t);
    zero_k<<<256, 256, 0, stream>>>(t1, 128 * 512);
    mgemm<float, 0, false, true><<<dim3(4, 1, 64), 256, 0, stream>>>(
        h_b, dW1t, nullptr, t1, 128, 512, 32768, 512, 512);
    head2_k<<<dim3(128), 256, 0, stream>>>(t1, db1, dW2, db2, out);
}